// Round 9
// baseline (193.345 us; speedup 1.0000x reference)
//
#include <hip/hip_runtime.h>

#define B_ 8192
#define IN_ 1024
#define OUT_ 256
#define E_ 16
#define KTOP 3
#define H_ 512
#define MAXSLOTS 26624   // 24576 + 16*127 rounded up
#define NTILES 208       // MAXSLOTS / 128
#define HBLK 32          // scatterscan blocks
#define GBLK 512         // gating blocks (16 rows each)

typedef __bf16 bf16;
typedef __bf16 bf16x4 __attribute__((ext_vector_type(4)));
typedef __bf16 bf16x8 __attribute__((ext_vector_type(8)));
typedef float f32x4 __attribute__((ext_vector_type(4)));

// async global->LDS, 16B per lane. LDS dest must be wave-uniform base + lane*16.
__device__ __forceinline__ void async16(const bf16* g, bf16* l) {
    __builtin_amdgcn_global_load_lds(
        (const __attribute__((address_space(1))) void*)g,
        (__attribute__((address_space(3))) void*)l,
        16, 0, 0);
}

// ================= stage1: gating + W transposes(vectorized) + inits + y zero =================
// blocks [0,512): gating 16 rows each; [512,2560): W1t; [2560,3072): W2t;
// [3072,3176): row_ids=-1; 3176: zero_row + tile_expert=-1; [3177,3689): y zero.
__global__ __launch_bounds__(256) void k_stage1(
    const float* __restrict__ x, const float* __restrict__ wg,
    const float* __restrict__ W1, const float* __restrict__ W2,
    bf16* __restrict__ xbf, int* __restrict__ top_idx, float* __restrict__ top_gate,
    int* __restrict__ partial,
    bf16* __restrict__ w1t, bf16* __restrict__ w2t,
    int* __restrict__ row_ids, bf16* __restrict__ zero_row, int* __restrict__ tile_expert,
    float* __restrict__ y) {
    __shared__ __align__(16) float smem[16448];  // 65.8 KB: wg planes (16 x 257 float4) / transpose tile
    __shared__ int lcnt[16];
    int bx = blockIdx.x;
    int t = threadIdx.x;
    if (bx < GBLK) {
        // ---- gating: 16 rows/block; wg staged as 16 planes [e4*4+jj][j4] of float4 ----
        float4* swgT4 = (float4*)smem;
        const float4* wg4 = (const float4*)wg;
        if (t < 16) lcnt[t] = 0;
#pragma unroll
        for (int i = 0; i < 16; i++) {
            int p = (t & 3) * 4 + ((t >> 2) & 3);
            int slot = i * 16 + (t >> 4);
            swgT4[p * 257 + slot] = wg4[i * 256 + t];
        }
        __syncthreads();
        int wv = t >> 6, lane = t & 63;
#pragma unroll
        for (int pr = 0; pr < 2; ++pr) {
            int row = bx * 16 + wv * 4 + pr * 2;   // rows row, row+1
            const float4* xra = (const float4*)(x + (size_t)row * IN_);
            const float4* xrb = (const float4*)(x + (size_t)(row + 1) * IN_);
            float4 xa[4], xb4[4];
#pragma unroll
            for (int q = 0; q < 4; q++) { xa[q] = xra[lane + 64 * q]; xb4[q] = xrb[lane + 64 * q]; }
#pragma unroll
            for (int q = 0; q < 4; q++) {
                bf16x4 ca, cb;
                ca[0] = (bf16)xa[q].x; ca[1] = (bf16)xa[q].y; ca[2] = (bf16)xa[q].z; ca[3] = (bf16)xa[q].w;
                cb[0] = (bf16)xb4[q].x; cb[1] = (bf16)xb4[q].y; cb[2] = (bf16)xb4[q].z; cb[3] = (bf16)xb4[q].w;
                *(bf16x4*)(xbf + (size_t)row * IN_ + (size_t)(lane + 64 * q) * 4) = ca;
                *(bf16x4*)(xbf + (size_t)(row + 1) * IN_ + (size_t)(lane + 64 * q) * 4) = cb;
            }
            float acca[16], accb[16];
#pragma unroll
            for (int e = 0; e < 16; e++) { acca[e] = 0.f; accb[e] = 0.f; }
#pragma unroll
            for (int q = 0; q < 4; q++) {
                float sa[4] = {xa[q].x, xa[q].y, xa[q].z, xa[q].w};
                float sb[4] = {xb4[q].x, xb4[q].y, xb4[q].z, xb4[q].w};
#pragma unroll
                for (int jj = 0; jj < 4; jj++) {
#pragma unroll
                    for (int e4 = 0; e4 < 4; e4++) {
                        float4 w4 = swgT4[(e4 * 4 + jj) * 257 + lane + 64 * q];
                        acca[e4 * 4 + 0] += sa[jj] * w4.x;
                        acca[e4 * 4 + 1] += sa[jj] * w4.y;
                        acca[e4 * 4 + 2] += sa[jj] * w4.z;
                        acca[e4 * 4 + 3] += sa[jj] * w4.w;
                        accb[e4 * 4 + 0] += sb[jj] * w4.x;
                        accb[e4 * 4 + 1] += sb[jj] * w4.y;
                        accb[e4 * 4 + 2] += sb[jj] * w4.z;
                        accb[e4 * 4 + 3] += sb[jj] * w4.w;
                    }
                }
            }
#pragma unroll
            for (int e = 0; e < 16; e++) {
#pragma unroll
                for (int s = 32; s > 0; s >>= 1) {
                    acca[e] += __shfl_xor(acca[e], s, 64);
                    accb[e] += __shfl_xor(accb[e], s, 64);
                }
            }
            if (lane < 2) {
                float v[16];
#pragma unroll
                for (int e = 0; e < 16; e++) v[e] = lane ? accb[e] : acca[e];
                int rsel = row + lane;
                int idx[KTOP];
                float val[KTOP];
#pragma unroll
                for (int k = 0; k < KTOP; k++) {
                    int best = 0;
                    float bv = v[0];
                    for (int e = 1; e < 16; e++) {
                        if (v[e] > bv) { bv = v[e]; best = e; }
                    }
                    idx[k] = best; val[k] = bv; v[best] = -1e30f;
                }
                float e1 = __expf(val[1] - val[0]);
                float e2 = __expf(val[2] - val[0]);
                float inv = 1.f / (1.f + e1 + e2);
                float g[KTOP] = {inv, e1 * inv, e2 * inv};
#pragma unroll
                for (int k = 0; k < KTOP; k++) {
                    top_idx[rsel * KTOP + k] = idx[k];
                    top_gate[rsel * KTOP + k] = g[k];
                    atomicAdd(&lcnt[idx[k]], 1);
                }
            }
        }
        __syncthreads();
        if (t < 16) partial[bx * 16 + t] = lcnt[t];
        return;
    }
    if (bx >= 3072) {
        if (bx < 3176) {            // row_ids = -1 (104*256 == MAXSLOTS)
            row_ids[(bx - 3072) * 256 + t] = -1;
        } else if (bx == 3176) {    // zero_row + tile_expert
#pragma unroll
            for (int i = 0; i < 4; i++) zero_row[t * 4 + i] = (bf16)0.f;
            if (t < NTILES) tile_expert[t] = -1;
        } else {                    // y zero: 512 blocks x 16 KB
            float4* y4 = (float4*)y + (size_t)(bx - 3177) * 1024;
            float4 z = {0.f, 0.f, 0.f, 0.f};
#pragma unroll
            for (int i = 0; i < 4; i++) y4[i * 256 + t] = z;
        }
        return;
    }
    // ---- W transpose+convert v2 (vectorized): in [E][K][N] f32 -> out [E][N][K] bf16 ----
    float (*tile)[65] = (float(*)[65])smem;   // 16.6 KB
    const float* in; bf16* out; int Kd, Nd, e, tk, tn;
    if (bx < 2560) {            // W1: 16 experts x (16 x 8) tiles
        int b1x = bx - 512;
        in = W1; out = w1t; Kd = IN_; Nd = H_;
        e = b1x >> 7; int tt = b1x & 127; tk = tt >> 3; tn = tt & 7;
    } else {                    // W2: 16 experts x (8 x 4) tiles
        int b2x = bx - 2560;
        in = W2; out = w2t; Kd = H_; Nd = OUT_;
        e = b2x >> 5; int tt = b2x & 31; tk = tt >> 2; tn = tt & 3;
    }
    const float* src = in + ((size_t)e * Kd + tk * 64) * Nd + (size_t)tn * 64;
    {
        int c4 = (t & 15) * 4;
#pragma unroll
        for (int p = 0; p < 4; p++) {
            int kr = p * 16 + (t >> 4);
            float4 v = *(const float4*)(src + (size_t)kr * Nd + c4);
            tile[kr][c4 + 0] = v.x;
            tile[kr][c4 + 1] = v.y;
            tile[kr][c4 + 2] = v.z;
            tile[kr][c4 + 3] = v.w;
        }
    }
    __syncthreads();
    bf16* dst = out + ((size_t)e * Nd + tn * 64) * Kd + (size_t)tk * 64;
    {
        int k8 = (t & 7) * 8;
#pragma unroll
        for (int p = 0; p < 2; p++) {
            int n = p * 32 + (t >> 3);
            bf16x8 o;
#pragma unroll
            for (int j = 0; j < 8; j++) o[j] = (bf16)tile[k8 + j][n];
            *(bf16x8*)(dst + (size_t)n * Kd + k8) = o;
        }
    }
}

// ---------------- scatterscan: scan of 512x16 partials + scatter, 32 blocks ----------------
// writes row_ids[slot]=token and slot_gate[slot]=gate (combine is folded into k_fused).
__global__ __launch_bounds__(256) void k_scatterscan(
    const int* __restrict__ top_idx, const float* __restrict__ top_gate,
    const int* __restrict__ partial,
    int* __restrict__ counts, int* __restrict__ tile_expert,
    int* __restrict__ row_ids, float* __restrict__ slot_gate,
    float* __restrict__ partial_imp) {
    __shared__ int segsum[32][16];   // [seg][e], 32 segs x 16 chunks each
    __shared__ int tote[16];
    __shared__ int sbase[16];
    __shared__ int lcnt[16];
    __shared__ float limp[16];
    int t = threadIdx.x;
    int blk = blockIdx.x;            // 32 blocks, each = 16 gating chunks = 768 gids
    int e = t & 15, sg2 = t >> 4;    // each thread covers segs sg2 and sg2+16
#pragma unroll
    for (int h = 0; h < 2; h++) {
        int seg = sg2 + h * 16;
        int s = 0;
#pragma unroll
        for (int i = 0; i < 16; i++) s += partial[(seg * 16 + i) * 16 + e];
        segsum[seg][e] = s;
    }
    if (t < 16) { lcnt[t] = 0; limp[t] = 0.f; }
    __syncthreads();
    if (t < 16) {
        int total = 0, pre = 0;
        for (int sg = 0; sg < 32; sg++) {
            int v = segsum[sg][t];
            total += v;
            if (sg < blk) pre += v;
        }
        tote[t] = total;
        segsum[0][t] = pre;
    }
    __syncthreads();
    if (t < 16) {
        int off = 0;
        for (int ee = 0; ee < 16; ee++) {
            if (ee == t) break;
            off += (tote[ee] + 127) & ~127;
        }
        sbase[t] = off + segsum[0][t];
        if (blk == 0) {
            counts[t] = tote[t];
            int pd = (tote[t] + 127) & ~127;
            for (int tt = off >> 7; tt < (off + pd) >> 7; ++tt) tile_expert[tt] = t;
        }
    }
    __syncthreads();
#pragma unroll
    for (int j = 0; j < 3; j++) {
        int gid = blk * 768 + j * 256 + t;
        int ee = top_idx[gid];
        float g = top_gate[gid];
        int rank = atomicAdd(&lcnt[ee], 1);
        atomicAdd(&limp[ee], g);
        int slot = sbase[ee] + rank;
        row_ids[slot] = gid / KTOP;
        slot_gate[slot] = g;
    }
    __syncthreads();
    if (t < 16) partial_imp[blk * 16 + t] = limp[t];
}

// ---------------- FUSED GEMM1+relu+GEMM2+combine: depth-2 counted-vmcnt pipeline ----------------
// R7-proven loop (no setprio). Epilogue: f32 atomicAdd of gate*(acc+bias) directly into y
// (eout + combine kernel eliminated; y pre-zeroed by stage1).
#define VWAIT(N) asm volatile("s_waitcnt vmcnt(" #N ")" ::: "memory")
__global__ __launch_bounds__(512) void k_fused(
    const bf16* __restrict__ xbf, const bf16* __restrict__ w1t,
    const float* __restrict__ b1, const bf16* __restrict__ w2t,
    const float* __restrict__ b2, const int* __restrict__ row_ids,
    const float* __restrict__ slot_gate,
    const int* __restrict__ tile_expert, const bf16* __restrict__ zero_row,
    float* __restrict__ y) {
    int bid = blockIdx.x;
    int tile = (bid & 7) * (NTILES / 8) + (bid >> 3);   // XCD-chunked bijection (208 = 8*26)
    int e = tile_expert[tile];
    if (e < 0) return;
    int slot_base = tile * 128;
    __shared__ __align__(16) bf16 smem[69632];   // 136 KB
    bf16* hs = smem;                             // 32768 elems
    bf16* pb0 = smem + 32768;
    bf16* pb1 = smem + 32768 + 12288;
    bf16* pb2 = smem + 32768 + 24576;
    int t = threadIdx.x;
    int cg = (t & 3) ^ ((t >> 3) & 3);           // pre-swizzled global k-vec for row m = t>>2
    int rid = row_ids[slot_base + (t >> 2)];
    const bf16* gA = ((rid >= 0) ? xbf + (size_t)rid * IN_ : zero_row) + cg * 8;
    const bf16* gB1[2];
    const bf16* gB2[2];
#pragma unroll
    for (int j = 0; j < 2; j++) {
        int m = j * 128 + (t >> 2);
        gB1[j] = w1t + ((size_t)e * H_ + m) * IN_ + cg * 8;     // + c*256*IN_ per chunk
        gB2[j] = w2t + ((size_t)e * OUT_ + m) * H_ + cg * 8;    // + c*256 + s*32
    }
    int w = t >> 6, lane = t & 63;
    int wm = (w & 1) * 64, wn = (w >> 1) * 64;   // 8 waves: 2x4 grid of 64x64 sub-tiles
    int lm = lane & 15, lq = lane >> 4;
    // fragment LDS indices (bf16x8 units), loop-invariant
    int aidx[4], bidx[4], hrow[4], hx[4];
#pragma unroll
    for (int i = 0; i < 4; i++) {
        int ra = wm + i * 16 + lm;
        int rb = wn + i * 16 + lm;
        aidx[i] = ra * 4 + (lq ^ ((ra >> 1) & 3));
        bidx[i] = rb * 4 + (lq ^ ((rb >> 1) & 3));
        hrow[i] = ra * 32;
        hx[i] = ra & 7;
    }
    // bias preload + pin (keeps vmcnt accounting clean inside the loop)
    float rbias1[2][4], rbias2[4];
#pragma unroll
    for (int c2 = 0; c2 < 2; ++c2)
#pragma unroll
        for (int ni = 0; ni < 4; ++ni) rbias1[c2][ni] = b1[e * H_ + c2 * 256 + wn + ni * 16 + lm];
#pragma unroll
    for (int ni = 0; ni < 4; ++ni) rbias2[ni] = b2[e * OUT_ + wn + ni * 16 + lm];
#pragma unroll
    for (int c2 = 0; c2 < 2; ++c2)
#pragma unroll
        for (int ni = 0; ni < 4; ++ni) asm volatile("" : "+v"(rbias1[c2][ni]));
#pragma unroll
    for (int ni = 0; ni < 4; ++ni) asm volatile("" : "+v"(rbias2[ni]));

    auto stageG1 = [&](bf16* buf, int c, int k) {
        async16(gA + k * 32, buf + t * 8);
        async16(gB1[0] + (size_t)c * (256 * IN_) + k * 32, buf + 4096 + t * 8);
        async16(gB1[1] + (size_t)c * (256 * IN_) + k * 32, buf + 4096 + (512 + t) * 8);
    };
    auto stageG2 = [&](bf16* buf, int c, int s) {
        const bf16* p0 = gB2[0] + c * 256 + s * 32;
        async16(p0, buf + t * 8);
        async16(gB2[1] + c * 256 + s * 32, buf + (512 + t) * 8);
        async16(p0, buf + t * 8);   // benign re-issue: uniform 3 loads per stage
    };

    f32x4 acc2[4][4] = {};
    bf16 *bufA = pb0, *bufB = pb1, *bufC = pb2;
    stageG1(bufA, 0, 0);
    stageG1(bufB, 0, 1);
#pragma unroll
    for (int c = 0; c < 2; ++c) {
        f32x4 acc1[4][4] = {};
        for (int k = 0; k < 32; ++k) {
            VWAIT(3);
            __builtin_amdgcn_s_barrier();
            __builtin_amdgcn_sched_barrier(0);
            const bf16x8* Av = (const bf16x8*)bufA;
            const bf16x8* Bv = (const bf16x8*)(bufA + 4096);
            bf16x8 af[4], bfv[4];
#pragma unroll
            for (int i = 0; i < 4; i++) af[i] = Av[aidx[i]];
#pragma unroll
            for (int i = 0; i < 4; i++) bfv[i] = Bv[bidx[i]];
#pragma unroll
            for (int mi = 0; mi < 4; mi++)
#pragma unroll
                for (int ni = 0; ni < 4; ni++)
                    acc1[mi][ni] = __builtin_amdgcn_mfma_f32_16x16x32_bf16(af[mi], bfv[ni], acc1[mi][ni], 0, 0, 0);
            if (k < 30) stageG1(bufC, c, k + 2);
            else        stageG2(bufC, c, k - 30);
            bf16* tmpb = bufA; bufA = bufB; bufB = bufC; bufC = tmpb;
        }
        // ---------- epilogue: bias + relu -> hs (XOR-swizzled to match G2 A-frag reads) ----------
#pragma unroll
        for (int mi = 0; mi < 4; mi++) {
#pragma unroll
            for (int ni = 0; ni < 4; ni++) {
                int col = wn + ni * 16 + lm;
                float bias = rbias1[c][ni];
#pragma unroll
                for (int r = 0; r < 4; r++) {
                    int row = wm + mi * 16 + lq * 4 + r;
                    float v = acc1[mi][ni][r] + bias;
                    v = v > 0.f ? v : 0.f;
                    hs[row * 256 + (((col >> 3) ^ (row & 7)) << 3) + (col & 7)] = (bf16)v;
                }
            }
        }
        asm volatile("s_waitcnt lgkmcnt(0)" ::: "memory");   // hs writes committed before barrier
#pragma unroll
        for (int s = 0; s < 8; ++s) {
            if (c == 1 && s == 7) { VWAIT(0); } else { VWAIT(3); }
            __builtin_amdgcn_s_barrier();
            __builtin_amdgcn_sched_barrier(0);
            const bf16x8* Hv = (const bf16x8*)hs;
            const bf16x8* B2v = (const bf16x8*)bufA;
            bf16x8 af[4], bfv[4];
#pragma unroll
            for (int i = 0; i < 4; i++) af[i] = Hv[hrow[i] + ((s * 4 + lq) ^ hx[i])];
#pragma unroll
            for (int i = 0; i < 4; i++) bfv[i] = B2v[bidx[i]];
#pragma unroll
            for (int mi = 0; mi < 4; mi++)
#pragma unroll
                for (int ni = 0; ni < 4; ni++)
                    acc2[mi][ni] = __builtin_amdgcn_mfma_f32_16x16x32_bf16(af[mi], bfv[ni], acc2[mi][ni], 0, 0, 0);
            if (s < 6)       stageG2(bufC, c, s + 2);
            else if (c == 0) stageG1(bufC, 1, s - 6);
            bf16* tmpb = bufA; bufA = bufB; bufB = bufC; bufC = tmpb;
        }
    }
    // ---------- combine epilogue: y[token] += gate * (acc2 + b2), f32 atomics ----------
#pragma unroll
    for (int mi = 0; mi < 4; mi++) {
#pragma unroll
        for (int r = 0; r < 4; r++) {
            int rowl = wm + mi * 16 + lq * 4 + r;
            int tok = row_ids[slot_base + rowl];
            if (tok < 0) continue;
            float g = slot_gate[slot_base + rowl];
            float* yr = y + (size_t)tok * OUT_;
#pragma unroll
            for (int ni = 0; ni < 4; ni++) {
                int colg = wn + ni * 16 + lm;
                atomicAdd(yr + colg, g * (acc2[mi][ni][r] + rbias2[ni]));
            }
        }
    }
}

// ---------------- loss (1 block) ----------------
__global__ __launch_bounds__(256) void k_loss(
    const float* __restrict__ partial_imp, const int* __restrict__ counts,
    float* __restrict__ loss_out) {
    int t = threadIdx.x;
    __shared__ float imp[16];
    if (t < 16) {
        float s = 0.f;
#pragma unroll
        for (int b = 0; b < HBLK; b++) s += partial_imp[b * 16 + t];
        imp[t] = s;
    }
    __syncthreads();
    if (t == 0) {
        float si = 0.f, sl = 0.f;
        for (int e = 0; e < E_; e++) { si += imp[e]; sl += (float)counts[e]; }
        float mi_ = si / (float)E_, ml_ = sl / (float)E_;
        float vi = 0.f, vl = 0.f;
        for (int e = 0; e < E_; e++) {
            float d = imp[e] - mi_; vi += d * d;
            float d2 = (float)counts[e] - ml_; vl += d2 * d2;
        }
        vi /= (float)(E_ - 1); vl /= (float)(E_ - 1);
        *loss_out = vi / (mi_ * mi_ + 1e-10f) + vl / (ml_ * ml_ + 1e-10f);
    }
}

extern "C" void kernel_launch(void* const* d_in, const int* in_sizes, int n_in,
                              void* d_out, int out_size, void* d_ws, size_t ws_size,
                              hipStream_t stream) {
    (void)in_sizes; (void)n_in; (void)out_size; (void)ws_size;
    const float* x = (const float*)d_in[0];
    const float* wgate = (const float*)d_in[1];
    const float* W1 = (const float*)d_in[2];
    const float* b1 = (const float*)d_in[3];
    const float* W2 = (const float*)d_in[4];
    const float* b2 = (const float*)d_in[5];
    float* y = (float*)d_out;  // [B*OUT] floats, then loss scalar at [B*OUT]

    char* p = (char*)d_ws;
    auto alloc = [&](size_t bytes) {
        char* q = p;
        p += (bytes + 255) & ~(size_t)255;
        return q;
    };
    bf16* xbf = (bf16*)alloc((size_t)B_ * IN_ * 2);          // 16 MB (live through fused!)
    bf16* w1t = (bf16*)alloc((size_t)E_ * H_ * IN_ * 2);     // 16 MB
    bf16* w2t = (bf16*)alloc((size_t)E_ * OUT_ * H_ * 2);    // 4 MB
    int* row_ids = (int*)alloc((size_t)MAXSLOTS * 4);
    float* slot_gate = (float*)alloc((size_t)MAXSLOTS * 4);
    int* top_idx = (int*)alloc((size_t)B_ * KTOP * 4);
    float* top_gate = (float*)alloc((size_t)B_ * KTOP * 4);
    int* counts = (int*)alloc(E_ * 4);
    int* partial = (int*)alloc((size_t)GBLK * E_ * 4);       // 32 KB gating hists
    float* partial_imp = (float*)alloc(HBLK * E_ * 4);
    int* tile_expert = (int*)alloc(NTILES * 4);
    bf16* zero_row = (bf16*)alloc(IN_ * 2);

    k_stage1<<<dim3(3689), dim3(256), 0, stream>>>(
        x, wgate, W1, W2, xbf, top_idx, top_gate, partial, w1t, w2t,
        row_ids, zero_row, tile_expert, y);
    k_scatterscan<<<dim3(HBLK), dim3(256), 0, stream>>>(
        top_idx, top_gate, partial, counts, tile_expert, row_ids, slot_gate, partial_imp);
    k_fused<<<dim3(NTILES), dim3(512), 0, stream>>>(
        xbf, w1t, b1, w2t, b2, row_ids, slot_gate, tile_expert, zero_row, y);
    k_loss<<<dim3(1), dim3(256), 0, stream>>>(
        partial_imp, counts, y + (size_t)B_ * OUT_);
}

// Round 10
// 178.223 us; speedup vs baseline: 1.0849x; 1.0849x over previous
//
#include <hip/hip_runtime.h>

#define B_ 8192
#define IN_ 1024
#define OUT_ 256
#define E_ 16
#define KTOP 3
#define H_ 512
#define MAXSLOTS 26624   // 24576 + 16*127 rounded up
#define NTILES 208       // MAXSLOTS / 128
#define HBLK 32          // scatterscan blocks
#define GBLK 256         // gating blocks (32 rows each)

typedef __bf16 bf16;
typedef __bf16 bf16x4 __attribute__((ext_vector_type(4)));
typedef __bf16 bf16x8 __attribute__((ext_vector_type(8)));
typedef float f32x4 __attribute__((ext_vector_type(4)));

// async global->LDS, 16B per lane. LDS dest must be wave-uniform base + lane*16.
__device__ __forceinline__ void async16(const bf16* g, bf16* l) {
    __builtin_amdgcn_global_load_lds(
        (const __attribute__((address_space(1))) void*)g,
        (__attribute__((address_space(3))) void*)l,
        16, 0, 0);
}

// ================= stage1: gating(conflict-free wg planes, 32 rows/block) + W transposes(vectorized) + inits =================
// blocks [0,256): gating 32 rows each; [256,2304): W1t; [2304,2816): W2t;
// [2816,2920): row_ids=-1; 2920: zero_row + tile_expert=-1.
__global__ __launch_bounds__(256) void k_stage1(
    const float* __restrict__ x, const float* __restrict__ wg,
    const float* __restrict__ W1, const float* __restrict__ W2,
    bf16* __restrict__ xbf, int* __restrict__ top_idx, float* __restrict__ top_gate,
    int* __restrict__ partial,
    bf16* __restrict__ w1t, bf16* __restrict__ w2t,
    int* __restrict__ row_ids, bf16* __restrict__ zero_row, int* __restrict__ tile_expert) {
    __shared__ __align__(16) float smem[16448];  // 65.8 KB: wg planes (16 x 257 float4) / transpose tile
    __shared__ int lcnt[16];
    int bx = blockIdx.x;
    int t = threadIdx.x;
    if (bx < GBLK) {
        // ---- gating: 32 rows/block; wg staged as 16 planes [e4*4+jj][j4] of float4 ----
        // plane stride 257 float4s: writes 2-way (free), reads conflict-free.
        float4* swgT4 = (float4*)smem;
        const float4* wg4 = (const float4*)wg;
        if (t < 16) lcnt[t] = 0;
#pragma unroll
        for (int i = 0; i < 16; i++) {
            int p = (t & 3) * 4 + ((t >> 2) & 3);
            int slot = i * 16 + (t >> 4);
            swgT4[p * 257 + slot] = wg4[i * 256 + t];
        }
        __syncthreads();
        int wv = t >> 6, lane = t & 63;
#pragma unroll
        for (int pr = 0; pr < 4; ++pr) {
            int row = bx * 32 + wv * 8 + pr * 2;   // rows row, row+1
            const float4* xra = (const float4*)(x + (size_t)row * IN_);
            const float4* xrb = (const float4*)(x + (size_t)(row + 1) * IN_);
            float4 xa[4], xb4[4];
#pragma unroll
            for (int q = 0; q < 4; q++) { xa[q] = xra[lane + 64 * q]; xb4[q] = xrb[lane + 64 * q]; }
#pragma unroll
            for (int q = 0; q < 4; q++) {
                bf16x4 ca, cb;
                ca[0] = (bf16)xa[q].x; ca[1] = (bf16)xa[q].y; ca[2] = (bf16)xa[q].z; ca[3] = (bf16)xa[q].w;
                cb[0] = (bf16)xb4[q].x; cb[1] = (bf16)xb4[q].y; cb[2] = (bf16)xb4[q].z; cb[3] = (bf16)xb4[q].w;
                *(bf16x4*)(xbf + (size_t)row * IN_ + (size_t)(lane + 64 * q) * 4) = ca;
                *(bf16x4*)(xbf + (size_t)(row + 1) * IN_ + (size_t)(lane + 64 * q) * 4) = cb;
            }
            float acca[16], accb[16];
#pragma unroll
            for (int e = 0; e < 16; e++) { acca[e] = 0.f; accb[e] = 0.f; }
#pragma unroll
            for (int q = 0; q < 4; q++) {
                float sa[4] = {xa[q].x, xa[q].y, xa[q].z, xa[q].w};
                float sb[4] = {xb4[q].x, xb4[q].y, xb4[q].z, xb4[q].w};
#pragma unroll
                for (int jj = 0; jj < 4; jj++) {
#pragma unroll
                    for (int e4 = 0; e4 < 4; e4++) {
                        float4 w4 = swgT4[(e4 * 4 + jj) * 257 + lane + 64 * q];
                        acca[e4 * 4 + 0] += sa[jj] * w4.x;
                        acca[e4 * 4 + 1] += sa[jj] * w4.y;
                        acca[e4 * 4 + 2] += sa[jj] * w4.z;
                        acca[e4 * 4 + 3] += sa[jj] * w4.w;
                        accb[e4 * 4 + 0] += sb[jj] * w4.x;
                        accb[e4 * 4 + 1] += sb[jj] * w4.y;
                        accb[e4 * 4 + 2] += sb[jj] * w4.z;
                        accb[e4 * 4 + 3] += sb[jj] * w4.w;
                    }
                }
            }
#pragma unroll
            for (int e = 0; e < 16; e++) {
#pragma unroll
                for (int s = 32; s > 0; s >>= 1) {
                    acca[e] += __shfl_xor(acca[e], s, 64);
                    accb[e] += __shfl_xor(accb[e], s, 64);
                }
            }
            if (lane < 2) {
                float v[16];
#pragma unroll
                for (int e = 0; e < 16; e++) v[e] = lane ? accb[e] : acca[e];
                int rsel = row + lane;
                int idx[KTOP];
                float val[KTOP];
#pragma unroll
                for (int k = 0; k < KTOP; k++) {
                    int best = 0;
                    float bv = v[0];
                    for (int e = 1; e < 16; e++) {
                        if (v[e] > bv) { bv = v[e]; best = e; }
                    }
                    idx[k] = best; val[k] = bv; v[best] = -1e30f;
                }
                float e1 = __expf(val[1] - val[0]);
                float e2 = __expf(val[2] - val[0]);
                float inv = 1.f / (1.f + e1 + e2);
                float g[KTOP] = {inv, e1 * inv, e2 * inv};
#pragma unroll
                for (int k = 0; k < KTOP; k++) {
                    top_idx[rsel * KTOP + k] = idx[k];
                    top_gate[rsel * KTOP + k] = g[k];
                    atomicAdd(&lcnt[idx[k]], 1);
                }
            }
        }
        __syncthreads();
        if (t < 16) partial[bx * 16 + t] = lcnt[t];
        return;
    }
    if (bx >= 2816) {
        if (bx < 2920) {            // row_ids = -1 (104*256 == MAXSLOTS)
            row_ids[(bx - 2816) * 256 + t] = -1;
        } else {                    // zero_row + tile_expert
#pragma unroll
            for (int i = 0; i < 4; i++) zero_row[t * 4 + i] = (bf16)0.f;
            if (t < NTILES) tile_expert[t] = -1;
        }
        return;
    }
    // ---- W transpose+convert v2 (vectorized): in [E][K][N] f32 -> out [E][N][K] bf16 ----
    float (*tile)[65] = (float(*)[65])smem;   // 16.6 KB
    const float* in; bf16* out; int Kd, Nd, e, tk, tn;
    if (bx < 2304) {            // W1: 16 experts x (16 x 8) tiles
        int b1x = bx - 256;
        in = W1; out = w1t; Kd = IN_; Nd = H_;
        e = b1x >> 7; int tt = b1x & 127; tk = tt >> 3; tn = tt & 7;
    } else {                    // W2: 16 experts x (8 x 4) tiles
        int b2x = bx - 2304;
        in = W2; out = w2t; Kd = H_; Nd = OUT_;
        e = b2x >> 5; int tt = b2x & 31; tk = tt >> 2; tn = tt & 3;
    }
    const float* src = in + ((size_t)e * Kd + tk * 64) * Nd + (size_t)tn * 64;
    {
        int c4 = (t & 15) * 4;
#pragma unroll
        for (int p = 0; p < 4; p++) {
            int kr = p * 16 + (t >> 4);
            float4 v = *(const float4*)(src + (size_t)kr * Nd + c4);
            tile[kr][c4 + 0] = v.x;
            tile[kr][c4 + 1] = v.y;
            tile[kr][c4 + 2] = v.z;
            tile[kr][c4 + 3] = v.w;
        }
    }
    __syncthreads();
    bf16* dst = out + ((size_t)e * Nd + tn * 64) * Kd + (size_t)tk * 64;
    {
        int k8 = (t & 7) * 8;
#pragma unroll
        for (int p = 0; p < 2; p++) {
            int n = p * 32 + (t >> 3);
            bf16x8 o;
#pragma unroll
            for (int j = 0; j < 8; j++) o[j] = (bf16)tile[k8 + j][n];
            *(bf16x8*)(dst + (size_t)n * Kd + k8) = o;
        }
    }
}

// ---------------- scatterscan: scan of 256x16 partials + scatter, 32 blocks ----------------
__global__ __launch_bounds__(256) void k_scatterscan(
    const int* __restrict__ top_idx, const float* __restrict__ top_gate,
    const int* __restrict__ partial,
    int* __restrict__ counts, int* __restrict__ tile_expert,
    int* __restrict__ row_ids, int* __restrict__ rowslot,
    float* __restrict__ partial_imp) {
    __shared__ int segsum[32][16];   // [seg][e], 32 segs x 8 gating-blocks each
    __shared__ int tote[16];
    __shared__ int sbase[16];
    __shared__ int lcnt[16];
    __shared__ float limp[16];
    int t = threadIdx.x;
    int blk = blockIdx.x;            // 32 blocks, each = 768 gids (gating blocks 8*blk..8*blk+7)
    int e = t & 15, sg2 = t >> 4;    // each thread covers segs sg2 and sg2+16
#pragma unroll
    for (int h = 0; h < 2; h++) {
        int seg = sg2 + h * 16;
        int s = 0;
#pragma unroll
        for (int i = 0; i < GBLK / 32; i++) s += partial[(seg * (GBLK / 32) + i) * 16 + e];
        segsum[seg][e] = s;
    }
    if (t < 16) { lcnt[t] = 0; limp[t] = 0.f; }
    __syncthreads();
    if (t < 16) {
        int total = 0, pre = 0;
        for (int sg = 0; sg < 32; sg++) {
            int v = segsum[sg][t];
            total += v;
            if (sg < blk) pre += v;
        }
        tote[t] = total;
        segsum[0][t] = pre;
    }
    __syncthreads();
    if (t < 16) {
        int off = 0;
        for (int ee = 0; ee < 16; ee++) {
            if (ee == t) break;
            off += (tote[ee] + 127) & ~127;
        }
        sbase[t] = off + segsum[0][t];
        if (blk == 0) {
            counts[t] = tote[t];
            int pd = (tote[t] + 127) & ~127;
            for (int tt = off >> 7; tt < (off + pd) >> 7; ++tt) tile_expert[tt] = t;
        }
    }
    __syncthreads();
#pragma unroll
    for (int j = 0; j < 3; j++) {
        int gid = blk * 768 + j * 256 + t;
        int ee = top_idx[gid];
        float g = top_gate[gid];
        int rank = atomicAdd(&lcnt[ee], 1);
        atomicAdd(&limp[ee], g);
        int slot = sbase[ee] + rank;
        row_ids[slot] = gid / KTOP;
        rowslot[gid] = slot;
    }
    __syncthreads();
    if (t < 16) partial_imp[blk * 16 + t] = limp[t];
}

// ---------------- FUSED GEMM1+relu+GEMM2: depth-2 counted-vmcnt pipeline (R4/R7-proven) ----------------
// + T1 XCD-chunked tile swizzle (R7-proven, FETCH halved). No setprio (R8 A/B: -3.7 us).
// BK=32 uniform steps (3 async16/thread each; G2 stages padded to 3 via benign re-issue).
// LDS 136 KB: hs[128][256] (64 KB) + 3 rotating 24 KB buffers (As 8 KB @0, B1s 16 KB @4096;
// B2s 16 KB aliases @0). Per iter: vmcnt(3); s_barrier; compute(k); issue stage(k+2).
#define VWAIT(N) asm volatile("s_waitcnt vmcnt(" #N ")" ::: "memory")
__global__ __launch_bounds__(512) void k_fused(
    const bf16* __restrict__ xbf, const bf16* __restrict__ w1t,
    const float* __restrict__ b1, const bf16* __restrict__ w2t,
    const float* __restrict__ b2, const int* __restrict__ row_ids,
    const int* __restrict__ tile_expert, const bf16* __restrict__ zero_row,
    bf16* __restrict__ eout) {
    int bid = blockIdx.x;
    int tile = (bid & 7) * (NTILES / 8) + (bid >> 3);   // XCD-chunked bijection (208 = 8*26)
    int e = tile_expert[tile];
    if (e < 0) return;
    int slot_base = tile * 128;
    __shared__ __align__(16) bf16 smem[69632];   // 136 KB
    bf16* hs = smem;                             // 32768 elems
    bf16* pb0 = smem + 32768;
    bf16* pb1 = smem + 32768 + 12288;
    bf16* pb2 = smem + 32768 + 24576;
    int t = threadIdx.x;
    int cg = (t & 3) ^ ((t >> 3) & 3);           // pre-swizzled global k-vec for row m = t>>2
    int rid = row_ids[slot_base + (t >> 2)];
    const bf16* gA = ((rid >= 0) ? xbf + (size_t)rid * IN_ : zero_row) + cg * 8;
    const bf16* gB1[2];
    const bf16* gB2[2];
#pragma unroll
    for (int j = 0; j < 2; j++) {
        int m = j * 128 + (t >> 2);
        gB1[j] = w1t + ((size_t)e * H_ + m) * IN_ + cg * 8;     // + c*256*IN_ per chunk
        gB2[j] = w2t + ((size_t)e * OUT_ + m) * H_ + cg * 8;    // + c*256 + s*32
    }
    int w = t >> 6, lane = t & 63;
    int wm = (w & 1) * 64, wn = (w >> 1) * 64;   // 8 waves: 2x4 grid of 64x64 sub-tiles
    int lm = lane & 15, lq = lane >> 4;
    // fragment LDS indices (bf16x8 units), loop-invariant
    int aidx[4], bidx[4], hrow[4], hx[4];
#pragma unroll
    for (int i = 0; i < 4; i++) {
        int ra = wm + i * 16 + lm;
        int rb = wn + i * 16 + lm;
        aidx[i] = ra * 4 + (lq ^ ((ra >> 1) & 3));
        bidx[i] = rb * 4 + (lq ^ ((rb >> 1) & 3));
        hrow[i] = ra * 32;
        hx[i] = ra & 7;
    }
    // bias preload + pin (keeps vmcnt accounting clean inside the loop)
    float rbias1[2][4], rbias2[4];
#pragma unroll
    for (int c2 = 0; c2 < 2; ++c2)
#pragma unroll
        for (int ni = 0; ni < 4; ++ni) rbias1[c2][ni] = b1[e * H_ + c2 * 256 + wn + ni * 16 + lm];
#pragma unroll
    for (int ni = 0; ni < 4; ++ni) rbias2[ni] = b2[e * OUT_ + wn + ni * 16 + lm];
#pragma unroll
    for (int c2 = 0; c2 < 2; ++c2)
#pragma unroll
        for (int ni = 0; ni < 4; ++ni) asm volatile("" : "+v"(rbias1[c2][ni]));
#pragma unroll
    for (int ni = 0; ni < 4; ++ni) asm volatile("" : "+v"(rbias2[ni]));

    auto stageG1 = [&](bf16* buf, int c, int k) {
        async16(gA + k * 32, buf + t * 8);
        async16(gB1[0] + (size_t)c * (256 * IN_) + k * 32, buf + 4096 + t * 8);
        async16(gB1[1] + (size_t)c * (256 * IN_) + k * 32, buf + 4096 + (512 + t) * 8);
    };
    auto stageG2 = [&](bf16* buf, int c, int s) {
        const bf16* p0 = gB2[0] + c * 256 + s * 32;
        async16(p0, buf + t * 8);
        async16(gB2[1] + c * 256 + s * 32, buf + (512 + t) * 8);
        async16(p0, buf + t * 8);   // benign re-issue: uniform 3 loads per stage
    };

    f32x4 acc2[4][4] = {};
    bf16 *bufA = pb0, *bufB = pb1, *bufC = pb2;
    stageG1(bufA, 0, 0);
    stageG1(bufB, 0, 1);
#pragma unroll
    for (int c = 0; c < 2; ++c) {
        f32x4 acc1[4][4] = {};
        for (int k = 0; k < 32; ++k) {
            VWAIT(3);
            __builtin_amdgcn_s_barrier();
            __builtin_amdgcn_sched_barrier(0);
            const bf16x8* Av = (const bf16x8*)bufA;
            const bf16x8* Bv = (const bf16x8*)(bufA + 4096);
            bf16x8 af[4], bfv[4];
#pragma unroll
            for (int i = 0; i < 4; i++) af[i] = Av[aidx[i]];
#pragma unroll
            for (int i = 0; i < 4; i++) bfv[i] = Bv[bidx[i]];
#pragma unroll
            for (int mi = 0; mi < 4; mi++)
#pragma unroll
                for (int ni = 0; ni < 4; ni++)
                    acc1[mi][ni] = __builtin_amdgcn_mfma_f32_16x16x32_bf16(af[mi], bfv[ni], acc1[mi][ni], 0, 0, 0);
            if (k < 30) stageG1(bufC, c, k + 2);
            else        stageG2(bufC, c, k - 30);
            bf16* tmpb = bufA; bufA = bufB; bufB = bufC; bufC = tmpb;
        }
        // ---------- epilogue: bias + relu -> hs (XOR-swizzled to match G2 A-frag reads) ----------
#pragma unroll
        for (int mi = 0; mi < 4; mi++) {
#pragma unroll
            for (int ni = 0; ni < 4; ni++) {
                int col = wn + ni * 16 + lm;
                float bias = rbias1[c][ni];
#pragma unroll
                for (int r = 0; r < 4; r++) {
                    int row = wm + mi * 16 + lq * 4 + r;
                    float v = acc1[mi][ni][r] + bias;
                    v = v > 0.f ? v : 0.f;
                    hs[row * 256 + (((col >> 3) ^ (row & 7)) << 3) + (col & 7)] = (bf16)v;
                }
            }
        }
        asm volatile("s_waitcnt lgkmcnt(0)" ::: "memory");   // hs writes committed before barrier
#pragma unroll
        for (int s = 0; s < 8; ++s) {
            if (c == 1 && s == 7) { VWAIT(0); } else { VWAIT(3); }
            __builtin_amdgcn_s_barrier();
            __builtin_amdgcn_sched_barrier(0);
            const bf16x8* Hv = (const bf16x8*)hs;
            const bf16x8* B2v = (const bf16x8*)bufA;
            bf16x8 af[4], bfv[4];
#pragma unroll
            for (int i = 0; i < 4; i++) af[i] = Hv[hrow[i] + ((s * 4 + lq) ^ hx[i])];
#pragma unroll
            for (int i = 0; i < 4; i++) bfv[i] = B2v[bidx[i]];
#pragma unroll
            for (int mi = 0; mi < 4; mi++)
#pragma unroll
                for (int ni = 0; ni < 4; ni++)
                    acc2[mi][ni] = __builtin_amdgcn_mfma_f32_16x16x32_bf16(af[mi], bfv[ni], acc2[mi][ni], 0, 0, 0);
            if (s < 6)       stageG2(bufC, c, s + 2);
            else if (c == 0) stageG1(bufC, 1, s - 6);
            bf16* tmpb = bufA; bufA = bufB; bufB = bufC; bufC = tmpb;
        }
    }
    // ---------- eout epilogue ----------
#pragma unroll
    for (int mi = 0; mi < 4; mi++) {
#pragma unroll
        for (int ni = 0; ni < 4; ni++) {
            int colg = wn + ni * 16 + lm;
            float bias = rbias2[ni];
#pragma unroll
            for (int r = 0; r < 4; r++) {
                int rowl = wm + mi * 16 + lq * 4 + r;
                eout[(size_t)(slot_base + rowl) * OUT_ + colg] = (bf16)(acc2[mi][ni][r] + bias);
            }
        }
    }
}

// ---------------- combine + loss (R7-proven) ----------------
__global__ __launch_bounds__(256) void k_combine(
    const bf16* __restrict__ eout, const int* __restrict__ rowslot,
    const float* __restrict__ top_gate, float* __restrict__ y,
    const float* __restrict__ partial_imp, const int* __restrict__ counts,
    float* __restrict__ loss_out) {
    int t = threadIdx.x;
    if (blockIdx.x == B_ / 4) {  // loss block
        __shared__ float imp[16];
        if (t < 16) {
            float s = 0.f;
#pragma unroll
            for (int b = 0; b < HBLK; b++) s += partial_imp[b * 16 + t];
            imp[t] = s;
        }
        __syncthreads();
        if (t == 0) {
            float si = 0.f, sl = 0.f;
            for (int e = 0; e < E_; e++) { si += imp[e]; sl += (float)counts[e]; }
            float mi_ = si / (float)E_, ml_ = sl / (float)E_;
            float vi = 0.f, vl = 0.f;
            for (int e = 0; e < E_; e++) {
                float d = imp[e] - mi_; vi += d * d;
                float d2 = (float)counts[e] - ml_; vl += d2 * d2;
            }
            vi /= (float)(E_ - 1); vl /= (float)(E_ - 1);
            *loss_out = vi / (mi_ * mi_ + 1e-10f) + vl / (ml_ * ml_ + 1e-10f);
        }
        return;
    }
    int b = blockIdx.x * 4 + (t >> 6);
    int lane = t & 63;
    int s0 = rowslot[b * 3], s1 = rowslot[b * 3 + 1], s2 = rowslot[b * 3 + 2];
    float g0 = top_gate[b * 3], g1 = top_gate[b * 3 + 1], g2 = top_gate[b * 3 + 2];
    bf16x4 v0 = *(const bf16x4*)(eout + (size_t)s0 * OUT_ + lane * 4);
    bf16x4 v1 = *(const bf16x4*)(eout + (size_t)s1 * OUT_ + lane * 4);
    bf16x4 v2 = *(const bf16x4*)(eout + (size_t)s2 * OUT_ + lane * 4);
    float4 r;
    r.x = g0 * (float)v0[0] + g1 * (float)v1[0] + g2 * (float)v2[0];
    r.y = g0 * (float)v0[1] + g1 * (float)v1[1] + g2 * (float)v2[1];
    r.z = g0 * (float)v0[2] + g1 * (float)v1[2] + g2 * (float)v2[2];
    r.w = g0 * (float)v0[3] + g1 * (float)v1[3] + g2 * (float)v2[3];
    ((float4*)y)[(size_t)b * 64 + lane] = r;
}

extern "C" void kernel_launch(void* const* d_in, const int* in_sizes, int n_in,
                              void* d_out, int out_size, void* d_ws, size_t ws_size,
                              hipStream_t stream) {
    (void)in_sizes; (void)n_in; (void)out_size; (void)ws_size;
    const float* x = (const float*)d_in[0];
    const float* wgate = (const float*)d_in[1];
    const float* W1 = (const float*)d_in[2];
    const float* b1 = (const float*)d_in[3];
    const float* W2 = (const float*)d_in[4];
    const float* b2 = (const float*)d_in[5];
    float* y = (float*)d_out;  // [B*OUT] floats, then loss scalar at [B*OUT]

    char* p = (char*)d_ws;
    auto alloc = [&](size_t bytes) {
        char* q = p;
        p += (bytes + 255) & ~(size_t)255;
        return q;
    };
    bf16* xbf = (bf16*)alloc((size_t)B_ * IN_ * 2);          // 16 MB (live through fused!)
    bf16* w1t = (bf16*)alloc((size_t)E_ * H_ * IN_ * 2);     // 16 MB
    bf16* w2t = (bf16*)alloc((size_t)E_ * OUT_ * H_ * 2);    // 4 MB
    bf16* eout = (bf16*)alloc((size_t)MAXSLOTS * OUT_ * 2);  // 13.6 MB
    int* row_ids = (int*)alloc((size_t)MAXSLOTS * 4);
    int* rowslot = (int*)alloc((size_t)B_ * KTOP * 4);
    int* top_idx = (int*)alloc((size_t)B_ * KTOP * 4);
    float* top_gate = (float*)alloc((size_t)B_ * KTOP * 4);
    int* counts = (int*)alloc(E_ * 4);
    int* partial = (int*)alloc((size_t)GBLK * E_ * 4);       // 16 KB gating hists
    float* partial_imp = (float*)alloc(HBLK * E_ * 4);
    int* tile_expert = (int*)alloc(NTILES * 4);
    bf16* zero_row = (bf16*)alloc(IN_ * 2);

    k_stage1<<<dim3(2921), dim3(256), 0, stream>>>(
        x, wgate, W1, W2, xbf, top_idx, top_gate, partial, w1t, w2t,
        row_ids, zero_row, tile_expert);
    k_scatterscan<<<dim3(HBLK), dim3(256), 0, stream>>>(
        top_idx, top_gate, partial, counts, tile_expert, row_ids, rowslot, partial_imp);
    k_fused<<<dim3(NTILES), dim3(512), 0, stream>>>(
        xbf, w1t, b1, w2t, b2, row_ids, tile_expert, zero_row, eout);
    k_combine<<<dim3(B_ / 4 + 1), dim3(256), 0, stream>>>(
        eout, rowslot, top_gate, y, partial_imp, counts, y + (size_t)B_ * OUT_);
}

// Round 11
// 177.455 us; speedup vs baseline: 1.0895x; 1.0043x over previous
//
#include <hip/hip_runtime.h>

#define B_ 8192
#define IN_ 1024
#define OUT_ 256
#define E_ 16
#define KTOP 3
#define H_ 512
#define MAXSLOTS 26624   // 24576 + 16*127 rounded up
#define NTILES 208       // MAXSLOTS / 128
#define HBLK 32          // scatterscan blocks
#define GBLK 256         // gating blocks (32 rows each)

typedef __bf16 bf16;
typedef __bf16 bf16x4 __attribute__((ext_vector_type(4)));
typedef __bf16 bf16x8 __attribute__((ext_vector_type(8)));
typedef float f32x4 __attribute__((ext_vector_type(4)));

// async global->LDS, 16B per lane. LDS dest must be wave-uniform base + lane*16.
__device__ __forceinline__ void async16(const bf16* g, bf16* l) {
    __builtin_amdgcn_global_load_lds(
        (const __attribute__((address_space(1))) void*)g,
        (__attribute__((address_space(3))) void*)l,
        16, 0, 0);
}

// ================= stage1: gating(conflict-free wg planes, 32 rows/block) + W transposes(vectorized) + inits =================
// blocks [0,256): gating 32 rows each; [256,2304): W1t; [2304,2816): W2t;
// [2816,2920): row_ids=-1; 2920: zero_row + tile_expert=-1.
__global__ __launch_bounds__(256) void k_stage1(
    const float* __restrict__ x, const float* __restrict__ wg,
    const float* __restrict__ W1, const float* __restrict__ W2,
    bf16* __restrict__ xbf, int* __restrict__ top_idx, float* __restrict__ top_gate,
    int* __restrict__ partial,
    bf16* __restrict__ w1t, bf16* __restrict__ w2t,
    int* __restrict__ row_ids, bf16* __restrict__ zero_row, int* __restrict__ tile_expert) {
    __shared__ __align__(16) float smem[16448];  // 65.8 KB: wg planes (16 x 257 float4) / transpose tile
    __shared__ int lcnt[16];
    int bx = blockIdx.x;
    int t = threadIdx.x;
    if (bx < GBLK) {
        // ---- gating: 32 rows/block; wg staged as 16 planes [e4*4+jj][j4] of float4 ----
        // plane stride 257 float4s: writes 2-way (free), reads conflict-free.
        float4* swgT4 = (float4*)smem;
        const float4* wg4 = (const float4*)wg;
        if (t < 16) lcnt[t] = 0;
#pragma unroll
        for (int i = 0; i < 16; i++) {
            int p = (t & 3) * 4 + ((t >> 2) & 3);
            int slot = i * 16 + (t >> 4);
            swgT4[p * 257 + slot] = wg4[i * 256 + t];
        }
        __syncthreads();
        int wv = t >> 6, lane = t & 63;
#pragma unroll
        for (int pr = 0; pr < 4; ++pr) {
            int row = bx * 32 + wv * 8 + pr * 2;   // rows row, row+1
            const float4* xra = (const float4*)(x + (size_t)row * IN_);
            const float4* xrb = (const float4*)(x + (size_t)(row + 1) * IN_);
            float4 xa[4], xb4[4];
#pragma unroll
            for (int q = 0; q < 4; q++) { xa[q] = xra[lane + 64 * q]; xb4[q] = xrb[lane + 64 * q]; }
#pragma unroll
            for (int q = 0; q < 4; q++) {
                bf16x4 ca, cb;
                ca[0] = (bf16)xa[q].x; ca[1] = (bf16)xa[q].y; ca[2] = (bf16)xa[q].z; ca[3] = (bf16)xa[q].w;
                cb[0] = (bf16)xb4[q].x; cb[1] = (bf16)xb4[q].y; cb[2] = (bf16)xb4[q].z; cb[3] = (bf16)xb4[q].w;
                *(bf16x4*)(xbf + (size_t)row * IN_ + (size_t)(lane + 64 * q) * 4) = ca;
                *(bf16x4*)(xbf + (size_t)(row + 1) * IN_ + (size_t)(lane + 64 * q) * 4) = cb;
            }
            float acca[16], accb[16];
#pragma unroll
            for (int e = 0; e < 16; e++) { acca[e] = 0.f; accb[e] = 0.f; }
#pragma unroll
            for (int q = 0; q < 4; q++) {
                float sa[4] = {xa[q].x, xa[q].y, xa[q].z, xa[q].w};
                float sb[4] = {xb4[q].x, xb4[q].y, xb4[q].z, xb4[q].w};
#pragma unroll
                for (int jj = 0; jj < 4; jj++) {
#pragma unroll
                    for (int e4 = 0; e4 < 4; e4++) {
                        float4 w4 = swgT4[(e4 * 4 + jj) * 257 + lane + 64 * q];
                        acca[e4 * 4 + 0] += sa[jj] * w4.x;
                        acca[e4 * 4 + 1] += sa[jj] * w4.y;
                        acca[e4 * 4 + 2] += sa[jj] * w4.z;
                        acca[e4 * 4 + 3] += sa[jj] * w4.w;
                        accb[e4 * 4 + 0] += sb[jj] * w4.x;
                        accb[e4 * 4 + 1] += sb[jj] * w4.y;
                        accb[e4 * 4 + 2] += sb[jj] * w4.z;
                        accb[e4 * 4 + 3] += sb[jj] * w4.w;
                    }
                }
            }
#pragma unroll
            for (int e = 0; e < 16; e++) {
#pragma unroll
                for (int s = 32; s > 0; s >>= 1) {
                    acca[e] += __shfl_xor(acca[e], s, 64);
                    accb[e] += __shfl_xor(accb[e], s, 64);
                }
            }
            if (lane < 2) {
                float v[16];
#pragma unroll
                for (int e = 0; e < 16; e++) v[e] = lane ? accb[e] : acca[e];
                int rsel = row + lane;
                int idx[KTOP];
                float val[KTOP];
#pragma unroll
                for (int k = 0; k < KTOP; k++) {
                    int best = 0;
                    float bv = v[0];
                    for (int e = 1; e < 16; e++) {
                        if (v[e] > bv) { bv = v[e]; best = e; }
                    }
                    idx[k] = best; val[k] = bv; v[best] = -1e30f;
                }
                float e1 = __expf(val[1] - val[0]);
                float e2 = __expf(val[2] - val[0]);
                float inv = 1.f / (1.f + e1 + e2);
                float g[KTOP] = {inv, e1 * inv, e2 * inv};
#pragma unroll
                for (int k = 0; k < KTOP; k++) {
                    top_idx[rsel * KTOP + k] = idx[k];
                    top_gate[rsel * KTOP + k] = g[k];
                    atomicAdd(&lcnt[idx[k]], 1);
                }
            }
        }
        __syncthreads();
        if (t < 16) partial[bx * 16 + t] = lcnt[t];
        return;
    }
    if (bx >= 2816) {
        if (bx < 2920) {            // row_ids = -1 (104*256 == MAXSLOTS)
            row_ids[(bx - 2816) * 256 + t] = -1;
        } else {                    // zero_row + tile_expert
#pragma unroll
            for (int i = 0; i < 4; i++) zero_row[t * 4 + i] = (bf16)0.f;
            if (t < NTILES) tile_expert[t] = -1;
        }
        return;
    }
    // ---- W transpose+convert v2 (vectorized): in [E][K][N] f32 -> out [E][N][K] bf16 ----
    float (*tile)[65] = (float(*)[65])smem;   // 16.6 KB
    const float* in; bf16* out; int Kd, Nd, e, tk, tn;
    if (bx < 2304) {            // W1: 16 experts x (16 x 8) tiles
        int b1x = bx - 256;
        in = W1; out = w1t; Kd = IN_; Nd = H_;
        e = b1x >> 7; int tt = b1x & 127; tk = tt >> 3; tn = tt & 7;
    } else {                    // W2: 16 experts x (8 x 4) tiles
        int b2x = bx - 2304;
        in = W2; out = w2t; Kd = H_; Nd = OUT_;
        e = b2x >> 5; int tt = b2x & 31; tk = tt >> 2; tn = tt & 3;
    }
    const float* src = in + ((size_t)e * Kd + tk * 64) * Nd + (size_t)tn * 64;
    {
        int c4 = (t & 15) * 4;
#pragma unroll
        for (int p = 0; p < 4; p++) {
            int kr = p * 16 + (t >> 4);
            float4 v = *(const float4*)(src + (size_t)kr * Nd + c4);
            tile[kr][c4 + 0] = v.x;
            tile[kr][c4 + 1] = v.y;
            tile[kr][c4 + 2] = v.z;
            tile[kr][c4 + 3] = v.w;
        }
    }
    __syncthreads();
    bf16* dst = out + ((size_t)e * Nd + tn * 64) * Kd + (size_t)tk * 64;
    {
        int k8 = (t & 7) * 8;
#pragma unroll
        for (int p = 0; p < 2; p++) {
            int n = p * 32 + (t >> 3);
            bf16x8 o;
#pragma unroll
            for (int j = 0; j < 8; j++) o[j] = (bf16)tile[k8 + j][n];
            *(bf16x8*)(dst + (size_t)n * Kd + k8) = o;
        }
    }
}

// ---------------- scatterscan: scan of 256x16 partials + scatter, 32 blocks ----------------
__global__ __launch_bounds__(256) void k_scatterscan(
    const int* __restrict__ top_idx, const float* __restrict__ top_gate,
    const int* __restrict__ partial,
    int* __restrict__ counts, int* __restrict__ tile_expert,
    int* __restrict__ row_ids, int* __restrict__ rowslot,
    float* __restrict__ partial_imp) {
    __shared__ int segsum[32][16];   // [seg][e], 32 segs x 8 gating-blocks each
    __shared__ int tote[16];
    __shared__ int sbase[16];
    __shared__ int lcnt[16];
    __shared__ float limp[16];
    int t = threadIdx.x;
    int blk = blockIdx.x;            // 32 blocks, each = 768 gids (gating blocks 8*blk..8*blk+7)
    int e = t & 15, sg2 = t >> 4;    // each thread covers segs sg2 and sg2+16
#pragma unroll
    for (int h = 0; h < 2; h++) {
        int seg = sg2 + h * 16;
        int s = 0;
#pragma unroll
        for (int i = 0; i < GBLK / 32; i++) s += partial[(seg * (GBLK / 32) + i) * 16 + e];
        segsum[seg][e] = s;
    }
    if (t < 16) { lcnt[t] = 0; limp[t] = 0.f; }
    __syncthreads();
    if (t < 16) {
        int total = 0, pre = 0;
        for (int sg = 0; sg < 32; sg++) {
            int v = segsum[sg][t];
            total += v;
            if (sg < blk) pre += v;
        }
        tote[t] = total;
        segsum[0][t] = pre;
    }
    __syncthreads();
    if (t < 16) {
        int off = 0;
        for (int ee = 0; ee < 16; ee++) {
            if (ee == t) break;
            off += (tote[ee] + 127) & ~127;
        }
        sbase[t] = off + segsum[0][t];
        if (blk == 0) {
            counts[t] = tote[t];
            int pd = (tote[t] + 127) & ~127;
            for (int tt = off >> 7; tt < (off + pd) >> 7; ++tt) tile_expert[tt] = t;
        }
    }
    __syncthreads();
#pragma unroll
    for (int j = 0; j < 3; j++) {
        int gid = blk * 768 + j * 256 + t;
        int ee = top_idx[gid];
        float g = top_gate[gid];
        int rank = atomicAdd(&lcnt[ee], 1);
        atomicAdd(&limp[ee], g);
        int slot = sbase[ee] + rank;
        row_ids[slot] = gid / KTOP;
        rowslot[gid] = slot;
    }
    __syncthreads();
    if (t < 16) partial_imp[blk * 16 + t] = limp[t];
}

// ---------------- FUSED GEMM1+relu+GEMM2: 4-buffer double-step pipeline ----------------
// 40 double-steps/block (vs 80): per double-step {VWAIT(0); barrier; issue 2 stages into the
// pair freed last step (post-barrier => race-free); compute 2 K-steps}. Stage->consume
// distance = 1 compute phase (~1000cyc) >= L2 latency (weights L2-resident via XCD swizzle).
// LDS 160 KB: hs[128][256] (64 KB) + 4 x 24 KB buffers. MFMA order identical to R10.
#define VWAIT(N) asm volatile("s_waitcnt vmcnt(" #N ")" ::: "memory")
#define G1STEP(BUF) do { \
    const bf16x8* _Av = (const bf16x8*)(BUF); \
    const bf16x8* _Bv = (const bf16x8*)((BUF) + 4096); \
    bf16x8 _af[4], _bfv[4]; \
    _Pragma("unroll") for (int _i = 0; _i < 4; _i++) _af[_i] = _Av[aidx[_i]]; \
    _Pragma("unroll") for (int _i = 0; _i < 4; _i++) _bfv[_i] = _Bv[bidx[_i]]; \
    _Pragma("unroll") for (int _mi = 0; _mi < 4; _mi++) \
        _Pragma("unroll") for (int _ni = 0; _ni < 4; _ni++) \
            acc1[_mi][_ni] = __builtin_amdgcn_mfma_f32_16x16x32_bf16(_af[_mi], _bfv[_ni], acc1[_mi][_ni], 0, 0, 0); \
} while (0)
#define G2STEP(BUF, S) do { \
    const bf16x8* _Hv = (const bf16x8*)hs; \
    const bf16x8* _B2v = (const bf16x8*)(BUF); \
    bf16x8 _af[4], _bfv[4]; \
    _Pragma("unroll") for (int _i = 0; _i < 4; _i++) { \
        _af[_i] = _Hv[hrow[_i] + (((S) * 4 + lq) ^ hx[_i])]; \
        _bfv[_i] = _B2v[bidx[_i]]; \
    } \
    _Pragma("unroll") for (int _mi = 0; _mi < 4; _mi++) \
        _Pragma("unroll") for (int _ni = 0; _ni < 4; _ni++) \
            acc2[_mi][_ni] = __builtin_amdgcn_mfma_f32_16x16x32_bf16(_af[_mi], _bfv[_ni], acc2[_mi][_ni], 0, 0, 0); \
} while (0)
__global__ __launch_bounds__(512) void k_fused(
    const bf16* __restrict__ xbf, const bf16* __restrict__ w1t,
    const float* __restrict__ b1, const bf16* __restrict__ w2t,
    const float* __restrict__ b2, const int* __restrict__ row_ids,
    const int* __restrict__ tile_expert, const bf16* __restrict__ zero_row,
    bf16* __restrict__ eout) {
    int bid = blockIdx.x;
    int tile = (bid & 7) * (NTILES / 8) + (bid >> 3);   // XCD-chunked bijection (208 = 8*26)
    int e = tile_expert[tile];
    if (e < 0) return;
    int slot_base = tile * 128;
    __shared__ __align__(16) bf16 smem[81920];   // 160 KB
    bf16* hs = smem;                             // 32768 elems
    bf16* pb0 = smem + 32768;
    bf16* pb1 = smem + 32768 + 12288;
    bf16* pb2 = smem + 32768 + 24576;
    bf16* pb3 = smem + 32768 + 36864;
    int t = threadIdx.x;
    int cg = (t & 3) ^ ((t >> 3) & 3);           // pre-swizzled global k-vec for row m = t>>2
    int rid = row_ids[slot_base + (t >> 2)];
    const bf16* gA = ((rid >= 0) ? xbf + (size_t)rid * IN_ : zero_row) + cg * 8;
    const bf16* gB1[2];
    const bf16* gB2[2];
#pragma unroll
    for (int j = 0; j < 2; j++) {
        int m = j * 128 + (t >> 2);
        gB1[j] = w1t + ((size_t)e * H_ + m) * IN_ + cg * 8;     // + c*256*IN_ per chunk
        gB2[j] = w2t + ((size_t)e * OUT_ + m) * H_ + cg * 8;    // + c*256 + s*32
    }
    int w = t >> 6, lane = t & 63;
    int wm = (w & 1) * 64, wn = (w >> 1) * 64;   // 8 waves: 2x4 grid of 64x64 sub-tiles
    int lm = lane & 15, lq = lane >> 4;
    // fragment LDS indices (bf16x8 units), loop-invariant
    int aidx[4], bidx[4], hrow[4], hx[4];
#pragma unroll
    for (int i = 0; i < 4; i++) {
        int ra = wm + i * 16 + lm;
        int rb = wn + i * 16 + lm;
        aidx[i] = ra * 4 + (lq ^ ((ra >> 1) & 3));
        bidx[i] = rb * 4 + (lq ^ ((rb >> 1) & 3));
        hrow[i] = ra * 32;
        hx[i] = ra & 7;
    }
    // bias preload + pin (keeps vmcnt accounting clean inside the loop)
    float rbias1[2][4], rbias2[4];
#pragma unroll
    for (int c2 = 0; c2 < 2; ++c2)
#pragma unroll
        for (int ni = 0; ni < 4; ++ni) rbias1[c2][ni] = b1[e * H_ + c2 * 256 + wn + ni * 16 + lm];
#pragma unroll
    for (int ni = 0; ni < 4; ++ni) rbias2[ni] = b2[e * OUT_ + wn + ni * 16 + lm];
#pragma unroll
    for (int c2 = 0; c2 < 2; ++c2)
#pragma unroll
        for (int ni = 0; ni < 4; ++ni) asm volatile("" : "+v"(rbias1[c2][ni]));
#pragma unroll
    for (int ni = 0; ni < 4; ++ni) asm volatile("" : "+v"(rbias2[ni]));

    auto stageG1 = [&](bf16* buf, int c, int k) {
        async16(gA + k * 32, buf + t * 8);
        async16(gB1[0] + (size_t)c * (256 * IN_) + k * 32, buf + 4096 + t * 8);
        async16(gB1[1] + (size_t)c * (256 * IN_) + k * 32, buf + 4096 + (512 + t) * 8);
    };
    auto stageG2 = [&](bf16* buf, int c, int s) {
        async16(gB2[0] + c * 256 + s * 32, buf + t * 8);
        async16(gB2[1] + c * 256 + s * 32, buf + (512 + t) * 8);
    };

    f32x4 acc2[4][4] = {};
    // compute pair (pX0,pX1), free/staging pair (pY0,pY1)
    bf16 *pX0 = pb0, *pX1 = pb1, *pY0 = pb2, *pY1 = pb3;
    stageG1(pX0, 0, 0);
    stageG1(pX1, 0, 1);
#pragma unroll
    for (int c = 0; c < 2; ++c) {
        f32x4 acc1[4][4] = {};
        for (int j = 0; j < 16; ++j) {           // double-steps: compute k=2j, 2j+1
            VWAIT(0);
            __builtin_amdgcn_s_barrier();
            __builtin_amdgcn_sched_barrier(0);
            if (j < 15) { stageG1(pY0, c, 2 * j + 2); stageG1(pY1, c, 2 * j + 3); }
            else        { stageG2(pY0, c, 0);         stageG2(pY1, c, 1); }
            G1STEP(pX0);
            G1STEP(pX1);
            bf16* t0 = pX0; pX0 = pY0; pY0 = t0;
            bf16* t1 = pX1; pX1 = pY1; pY1 = t1;
        }
        // ---------- epilogue: bias + relu -> hs (XOR-swizzled to match G2 A-frag reads) ----------
#pragma unroll
        for (int mi = 0; mi < 4; mi++) {
#pragma unroll
            for (int ni = 0; ni < 4; ni++) {
                int col = wn + ni * 16 + lm;
                float bias = rbias1[c][ni];
#pragma unroll
                for (int r = 0; r < 4; r++) {
                    int row = wm + mi * 16 + lq * 4 + r;
                    float v = acc1[mi][ni][r] + bias;
                    v = v > 0.f ? v : 0.f;
                    hs[row * 256 + (((col >> 3) ^ (row & 7)) << 3) + (col & 7)] = (bf16)v;
                }
            }
        }
        asm volatile("s_waitcnt lgkmcnt(0)" ::: "memory");   // hs writes committed before barrier
        for (int g = 0; g < 4; ++g) {            // double-steps: compute s=2g, 2g+1
            VWAIT(0);
            __builtin_amdgcn_s_barrier();
            __builtin_amdgcn_sched_barrier(0);
            if (g < 3)       { stageG2(pY0, c, 2 * g + 2); stageG2(pY1, c, 2 * g + 3); }
            else if (c == 0) { stageG1(pY0, 1, 0);         stageG1(pY1, 1, 1); }
            G2STEP(pX0, 2 * g);
            G2STEP(pX1, 2 * g + 1);
            bf16* t0 = pX0; pX0 = pY0; pY0 = t0;
            bf16* t1 = pX1; pX1 = pY1; pY1 = t1;
        }
    }
    // ---------- eout epilogue ----------
#pragma unroll
    for (int mi = 0; mi < 4; mi++) {
#pragma unroll
        for (int ni = 0; ni < 4; ni++) {
            int colg = wn + ni * 16 + lm;
            float bias = rbias2[ni];
#pragma unroll
            for (int r = 0; r < 4; r++) {
                int rowl = wm + mi * 16 + lq * 4 + r;
                eout[(size_t)(slot_base + rowl) * OUT_ + colg] = (bf16)(acc2[mi][ni][r] + bias);
            }
        }
    }
}

// ---------------- combine + loss (R10-proven) ----------------
__global__ __launch_bounds__(256) void k_combine(
    const bf16* __restrict__ eout, const int* __restrict__ rowslot,
    const float* __restrict__ top_gate, float* __restrict__ y,
    const float* __restrict__ partial_imp, const int* __restrict__ counts,
    float* __restrict__ loss_out) {
    int t = threadIdx.x;
    if (blockIdx.x == B_ / 4) {  // loss block
        __shared__ float imp[16];
        if (t < 16) {
            float s = 0.f;
#pragma unroll
            for (int b = 0; b < HBLK; b++) s += partial_imp[b * 16 + t];
            imp[t] = s;
        }
        __syncthreads();
        if (t == 0) {
            float si = 0.f, sl = 0.f;
            for (int e = 0; e < E_; e++) { si += imp[e]; sl += (float)counts[e]; }
            float mi_ = si / (float)E_, ml_ = sl / (float)E_;
            float vi = 0.f, vl = 0.f;
            for (int e = 0; e < E_; e++) {
                float d = imp[e] - mi_; vi += d * d;
                float d2 = (float)counts[e] - ml_; vl += d2 * d2;
            }
            vi /= (float)(E_ - 1); vl /= (float)(E_ - 1);
            *loss_out = vi / (mi_ * mi_ + 1e-10f) + vl / (ml_ * ml_ + 1e-10f);
        }
        return;
    }
    int b = blockIdx.x * 4 + (t >> 6);
    int lane = t & 63;
    int s0 = rowslot[b * 3], s1 = rowslot[b * 3 + 1], s2 = rowslot[b * 3 + 2];
    float g0 = top_gate[b * 3], g1 = top_gate[b * 3 + 1], g2 = top_gate[b * 3 + 2];
    bf16x4 v0 = *(const bf16x4*)(eout + (size_t)s0 * OUT_ + lane * 4);
    bf16x4 v1 = *(const bf16x4*)(eout + (size_t)s1 * OUT_ + lane * 4);
    bf16x4 v2 = *(const bf16x4*)(eout + (size_t)s2 * OUT_ + lane * 4);
    float4 r;
    r.x = g0 * (float)v0[0] + g1 * (float)v1[0] + g2 * (float)v2[0];
    r.y = g0 * (float)v0[1] + g1 * (float)v1[1] + g2 * (float)v2[1];
    r.z = g0 * (float)v0[2] + g1 * (float)v1[2] + g2 * (float)v2[2];
    r.w = g0 * (float)v0[3] + g1 * (float)v1[3] + g2 * (float)v2[3];
    ((float4*)y)[(size_t)b * 64 + lane] = r;
}

extern "C" void kernel_launch(void* const* d_in, const int* in_sizes, int n_in,
                              void* d_out, int out_size, void* d_ws, size_t ws_size,
                              hipStream_t stream) {
    (void)in_sizes; (void)n_in; (void)out_size; (void)ws_size;
    const float* x = (const float*)d_in[0];
    const float* wgate = (const float*)d_in[1];
    const float* W1 = (const float*)d_in[2];
    const float* b1 = (const float*)d_in[3];
    const float* W2 = (const float*)d_in[4];
    const float* b2 = (const float*)d_in[5];
    float* y = (float*)d_out;  // [B*OUT] floats, then loss scalar at [B*OUT]

    char* p = (char*)d_ws;
    auto alloc = [&](size_t bytes) {
        char* q = p;
        p += (bytes + 255) & ~(size_t)255;
        return q;
    };
    bf16* xbf = (bf16*)alloc((size_t)B_ * IN_ * 2);          // 16 MB (live through fused!)
    bf16* w1t = (bf16*)alloc((size_t)E_ * H_ * IN_ * 2);     // 16 MB
    bf16* w2t = (bf16*)alloc((size_t)E_ * OUT_ * H_ * 2);    // 4 MB
    bf16* eout = (bf16*)alloc((size_t)MAXSLOTS * OUT_ * 2);  // 13.6 MB
    int* row_ids = (int*)alloc((size_t)MAXSLOTS * 4);
    int* rowslot = (int*)alloc((size_t)B_ * KTOP * 4);
    int* top_idx = (int*)alloc((size_t)B_ * KTOP * 4);
    float* top_gate = (float*)alloc((size_t)B_ * KTOP * 4);
    int* counts = (int*)alloc(E_ * 4);
    int* partial = (int*)alloc((size_t)GBLK * E_ * 4);       // 16 KB gating hists
    float* partial_imp = (float*)alloc(HBLK * E_ * 4);
    int* tile_expert = (int*)alloc(NTILES * 4);
    bf16* zero_row = (bf16*)alloc(IN_ * 2);

    k_stage1<<<dim3(2921), dim3(256), 0, stream>>>(
        x, wgate, W1, W2, xbf, top_idx, top_gate, partial, w1t, w2t,
        row_ids, zero_row, tile_expert);
    k_scatterscan<<<dim3(HBLK), dim3(256), 0, stream>>>(
        top_idx, top_gate, partial, counts, tile_expert, row_ids, rowslot, partial_imp);
    k_fused<<<dim3(NTILES), dim3(512), 0, stream>>>(
        xbf, w1t, b1, w2t, b2, row_ids, tile_expert, zero_row, eout);
    k_combine<<<dim3(B_ / 4 + 1), dim3(256), 0, stream>>>(
        eout, rowslot, top_gate, y, partial_imp, counts, y + (size_t)B_ * OUT_);
}